// Round 7
// baseline (169.836 us; speedup 1.0000x reference)
//
#include <hip/hip_runtime.h>
#include <hip/hip_bf16.h>

#define N_ 32
#define C_ 128
#define H_ 48
#define W_ 48
#define P_ (H_*W_)   // 2304
#define K_ 64
#define S_ 4
#define L_ 3
#define R_ 21
#define NB_ 72       // P_/32 pixel tiles per image
#define M_ 512       // total logit rows
#define CH_ 9        // xnG chunks (256 px each)
#define CHV_ 36      // vlad split-K chunks (64 px each)
#define NBK_ 1152    // 64-px norm blocks in k_prep (N_*P_/64)

typedef __hip_bfloat16 bf16;
typedef __attribute__((ext_vector_type(8))) short   bf16x8;
typedef __attribute__((ext_vector_type(8))) unsigned short u16x8;
typedef __attribute__((ext_vector_type(4))) unsigned short u16x4;
typedef __attribute__((ext_vector_type(4))) float   f32x4;

__device__ __forceinline__ float b2f(bf16 v){ return __bfloat162float(v); }
__device__ __forceinline__ float u2f(unsigned short u){
  union { unsigned i; float f; } v; v.i = ((unsigned)u) << 16; return v.f;
}
__device__ __forceinline__ unsigned short f2u(float f){
  bf16 h = __float2bfloat16(f);
  return *(unsigned short*)&h;
}

// wave-uniform dtype probe: 1 if x is fp32, 0 if bf16 (reads fixed 1024-elem window).
__device__ __forceinline__ int is_f32(const unsigned short* __restrict__ xb){
  int lane = threadIdx.x & 63;
  int w = 0;
  #pragma unroll
  for (int i=0;i<16;++i){
    int e = (xb[lane*16 + i] >> 7) & 0xFF;
    w += (e >= 0x8E) ? 1 : 0;
  }
  unsigned long long b = __ballot(w > 0);
  return __popcll(b) > 32;
}

// region membership for global region index r (0..20) at pixel (h,w); bf16 1.0/0.0 bits
__device__ __forceinline__ unsigned short region_bit(int r, int h, int w){
  bool m;
  if (r == 0){
    m = true;
  } else if (r < 5){
    int q = r-1, i = q>>1, j = q&1;
    m = (h>=16*i)&&(h<16*i+32)&&(w>=16*j)&&(w<16*j+32);
  } else if (r < 21){
    int q = r-5, i = q>>2, j = q&3;
    m = (h>=10*i-1)&&(h<10*i+19)&&(w>=10*j-1)&&(w<10*j+19);
  } else {
    m = false;
  }
  return m ? (unsigned short)0x3F80 : (unsigned short)0;
}

// ---------- K_A: fused k_wall (blocks >= NBK_) + 64-px k_norm (blocks < NBK_) ----------
// Norm blocks: streamed 2-pass sum-of-squares (volatile pass 1 defeats CSE -> ~50 VGPR,
// 6 blocks/CU); xnF emitted via packed scalar LDS gathers (no second tile, 2 barriers).
__global__ __launch_bounds__(256, 6) void k_prep(const void* __restrict__ cvw, const void* __restrict__ csw,
                                                 const void* __restrict__ caw, const void* __restrict__ x,
                                                 bf16* __restrict__ WallF, bf16* __restrict__ xnF,
                                                 bf16* __restrict__ xnG){
  int bid = blockIdx.x, t = threadIdx.x;
  int f32 = is_f32((const unsigned short*)x);
  if (bid >= NBK_){
    // ---- WallF build: frag f = ((rt*4+ks)*64 + lane)*8 + j ----
    int i = (bid - NBK_)*256 + t;                  // 0..65535
    int j = i&7, lane = (i>>3)&63, ks = (i>>9)&3, rt = (i>>11)&31;
    int row = rt*16 + (lane&15);
    int c   = ks*32 + ((lane>>4)&3)*8 + j;
    int s = row*C_ + c;
    float v;
    if (s < 8192)       v = f32 ? ((const float*)cvw)[s]        : b2f(((const bf16*)cvw)[s]);
    else if (s < 40960) v = f32 ? ((const float*)csw)[s-8192]   : b2f(((const bf16*)csw)[s-8192]);
    else                v = f32 ? ((const float*)caw)[s-40960]  : b2f(((const bf16*)caw)[s-40960]);
    WallF[i] = __float2bfloat16(v);
    return;
  }

  // ---- k_norm role: 64-px tile ----
  __shared__ float sred[4][64];
  __shared__ __align__(16) unsigned short tile[128][72];    // 18432 B, 144B rows (16B-mult)
  int n = bid / (P_/64), tb = bid % (P_/64);      // tb 0..35
  int p0 = tb*64;
  int px = t&63, chh = t>>6, c0 = chh*32;

  size_t off = ((size_t)n*C_ + c0)*P_ + p0 + px;
  float ss = 0.f;
  if (f32){
    const volatile float* xb = (const volatile float*)x + off;
    #pragma unroll
    for (int j8=0;j8<4;++j8){
      float tv[8];
      #pragma unroll
      for (int j=0;j<8;++j) tv[j] = xb[(size_t)(j8*8+j)*P_];
      #pragma unroll
      for (int j=0;j<8;++j) ss += tv[j]*tv[j];
    }
  } else {
    const volatile unsigned short* xb = (const volatile unsigned short*)x + off;
    #pragma unroll
    for (int j8=0;j8<4;++j8){
      float tv[8];
      #pragma unroll
      for (int j=0;j<8;++j) tv[j] = u2f(xb[(size_t)(j8*8+j)*P_]);
      #pragma unroll
      for (int j=0;j<8;++j) ss += tv[j]*tv[j];
    }
  }
  sred[chh][px] = ss;
  __syncthreads();
  float invn = 1.f / fmaxf(sqrtf(sred[0][px] + sred[1][px] + sred[2][px] + sred[3][px]), 1e-12f);

  // pass 2: reload (L1/L2-warm), normalize, write tile[c][px]
  if (f32){
    const float* xb = (const float*)x + off;
    #pragma unroll
    for (int j8=0;j8<4;++j8){
      float tv[8];
      #pragma unroll
      for (int j=0;j<8;++j) tv[j] = xb[(size_t)(j8*8+j)*P_];
      #pragma unroll
      for (int j=0;j<8;++j) tile[c0 + j8*8 + j][px] = f2u(tv[j]*invn);
    }
  } else {
    const unsigned short* xb = (const unsigned short*)x + off;
    #pragma unroll
    for (int j8=0;j8<4;++j8){
      float tv[8];
      #pragma unroll
      for (int j=0;j<8;++j) tv[j] = u2f(xb[(size_t)(j8*8+j)*P_]);
      #pragma unroll
      for (int j=0;j<8;++j) tile[c0 + j8*8 + j][px] = f2u(tv[j]*invn);
    }
  }
  __syncthreads();

  // ---- emit xnG: chunk ch = tb>>2, sub-64px slot sub = tb&3 ----
  {
    size_t gbase = (size_t)(n*CH_ + (tb>>2))*4096 + (size_t)(tb&3)*1024;
    u16x8* out = (u16x8*)xnG;
    #pragma unroll
    for (int it=0;it<4;++it){
      int o2 = t + it*256;                         // 0..1023
      int lane = o2&63, half = (o2>>6)&1, wvv = (o2>>7)&3, kslL = (o2>>9)&1;
      int c   = wvv*32 + half*16 + (lane&15);
      int plL = kslL*32 + ((lane>>4)&3)*8;
      out[gbase + o2] = *(const u16x8*)&tile[c][plL];
    }
  }
  // ---- emit xnF: 2 gemm-tiles, packed scalar gathers from tile ----
  {
    size_t fbase = (size_t)(n*NB_ + tb*2)*512;
    u16x8* out = (u16x8*)xnF;
    #pragma unroll
    for (int it=0;it<4;++it){
      int o = t + it*256;                          // 0..1023
      int lane = o&63, half = (o>>6)&1, ks = (o>>7)&3, pblL = (o>>9)&1;
      int pxr = pblL*32 + half*16 + (lane&15);
      int cc  = ks*32 + ((lane>>4)&3)*8;
      u16x8 pk;
      #pragma unroll
      for (int j=0;j<8;++j) pk[j] = tile[cc+j][pxr];
      out[fbase + o] = pk;
    }
  }
}

// ---------- K_B: fused 512-row MFMA GEMM + softmax + MFMA region sums ----------
// grid (NB_=72, N_=32), 512 thr / 8 waves; LDS exactly 40960 B -> 4 blocks/CU (32 waves).
__global__ __launch_bounds__(512, 4) void k_gemm(const bf16* __restrict__ WallF,
                                                 const bf16* __restrict__ xnF,
                                                 unsigned short* __restrict__ a,
                                                 float* __restrict__ salPart){
  __shared__ __align__(16) unsigned short ldsU[320][40];    // 25600 B
  __shared__ __align__(16) unsigned short appS[192][40];    // 15360 B
  int n = blockIdx.y, pb = blockIdx.x;
  int p0 = pb*32;
  int t = threadIdx.x, w = t>>6, l = t&63;
  int mrow = l&15, quad = l>>4;

  const bf16* Af = WallF + ((size_t)(w*4)*4)*512 + l*8;    // + (rtl*4+ks)*512
  const bf16* Bf = xnF + (size_t)(n*NB_ + pb)*4096 + l*8;  // + (ks*2+half)*512

  f32x4 acc[4][2];
  #pragma unroll
  for (int rtl=0;rtl<4;++rtl){ acc[rtl][0] = (f32x4){0,0,0,0}; acc[rtl][1] = (f32x4){0,0,0,0}; }

  #pragma unroll
  for (int ks=0;ks<4;++ks){
    bf16x8 b0 = *(const bf16x8*)(Bf + (ks*2+0)*512);
    bf16x8 b1 = *(const bf16x8*)(Bf + (ks*2+1)*512);
    #pragma unroll
    for (int rtl=0;rtl<4;++rtl){
      bf16x8 af = *(const bf16x8*)(Af + (rtl*4+ks)*512);
      acc[rtl][0] = __builtin_amdgcn_mfma_f32_16x16x32_bf16(af, b0, acc[rtl][0], 0,0,0);
      acc[rtl][1] = __builtin_amdgcn_mfma_f32_16x16x32_bf16(af, b1, acc[rtl][1], 0,0,0);
    }
  }

  // C/D: col = lane&15, row = quad*4 + reg. Wave-uniform routing by row range.
  #pragma unroll
  for (int rtl=0;rtl<4;++rtl){
    int row0 = w*64 + rtl*16;
    if (row0 < 64){                       // scores, k-major
      #pragma unroll
      for (int ct=0;ct<2;++ct)
        #pragma unroll
        for (int r=0;r<4;++r)
          ldsU[row0 + quad*4 + r][ct*16 + mrow] = f2u(acc[rtl][ct][r]);
    } else if (row0 < 320){               // shadows, s-major: row 64 + s*64 + k
      #pragma unroll
      for (int ct=0;ct<2;++ct)
        #pragma unroll
        for (int r=0;r<4;++r){
          int sr = row0 + quad*4 + r - 64;                  // = k*4 + s
          ldsU[64 + (sr&3)*64 + (sr>>2)][ct*16 + mrow] = f2u(acc[rtl][ct][r]);
        }
    } else {                              // app rows, relu'd, direct to appS
      int ar0 = row0 - 320 + quad*4;
      #pragma unroll
      for (int ct=0;ct<2;++ct)
        #pragma unroll
        for (int r=0;r<4;++r)
          appS[ar0 + r][ct*16 + mrow] = f2u(fmaxf(acc[rtl][ct][r], 0.f));
    }
  }
  __syncthreads();   // the only barrier

  // ---- softmax: lane = k, wave w = pixel-group (4 px). 5 x ds_read_b64, read-only. ----
  {
    u16x4 s4  = *(const u16x4*)&ldsU[l      ][w*4];
    u16x4 h0v = *(const u16x4*)&ldsU[64  + l][w*4];
    u16x4 h1v = *(const u16x4*)&ldsU[128 + l][w*4];
    u16x4 h2v = *(const u16x4*)&ldsU[192 + l][w*4];
    u16x4 h3v = *(const u16x4*)&ldsU[256 + l][w*4];
    float ez[4], Zr[4];
    #pragma unroll
    for (int j=0;j<4;++j){ ez[j] = __expf(u2f((unsigned short)s4[j])); Zr[j] = ez[j]; }
    #pragma unroll
    for (int st=1; st<64; st<<=1){
      #pragma unroll
      for (int j=0;j<4;++j) Zr[j] += __shfl_xor(Zr[j], st);
    }
    size_t tile = (size_t)n*NB_ + pb;
    #pragma unroll
    for (int j=0;j<4;++j){
      float e0 = ez[j];
      float den = e0 + __expf(u2f((unsigned short)h0v[j]))
                     + __expf(u2f((unsigned short)h1v[j]))
                     + __expf(u2f((unsigned short)h2v[j]))
                     + __expf(u2f((unsigned short)h3v[j]));
      a[tile*2048 + (size_t)(w*4+j)*64 + l] = f2u(__fdividef(e0*e0, Zr[j]*den));
    }
  }

  // ---- region sums via MFMA: salPart[tile][k][r] = sum_p app[k][p] * M[r][p] ----
  bf16x8 bm0;
  #pragma unroll
  for (int j=0;j<8;++j){
    int p = p0 + quad*8 + j;
    int h = p/48, wc = p - h*48;
    bm0[j] = (short)region_bit(mrow, h, wc);
  }
  size_t tile = (size_t)n*NB_ + pb;
  float* sp = salPart + tile*(K_*R_);
  if (w < 4){
    #pragma unroll
    for (int i=0;i<2;++i){
      int rt = w*2 + i;
      bf16x8 af = *(const bf16x8*)&appS[rt*16 + mrow][quad*8];
      f32x4 r0 = (f32x4){0,0,0,0};
      r0 = __builtin_amdgcn_mfma_f32_16x16x32_bf16(af, bm0, r0, 0,0,0);
      int kb = rt*16 + quad*4;
      if (rt < 4){                       // level0: region col 0 only
        if (mrow == 0){
          #pragma unroll
          for (int r=0;r<4;++r) sp[(size_t)(kb+r)*R_] = r0[r];
        }
      } else {                           // level1: cols 1..4
        if (mrow >= 1 && mrow <= 4){
          #pragma unroll
          for (int r=0;r<4;++r) sp[(size_t)(kb+r-64)*R_ + mrow] = r0[r];
        }
      }
    }
  } else {
    int rt = 8 + (w-4);                  // level2: cols 5..20
    bf16x8 bm1;
    #pragma unroll
    for (int j=0;j<8;++j){
      int p = p0 + quad*8 + j;
      int h = p/48, wc = p - h*48;
      bm1[j] = (short)region_bit(16 + mrow, h, wc);
    }
    bf16x8 af = *(const bf16x8*)&appS[rt*16 + mrow][quad*8];
    f32x4 r0 = (f32x4){0,0,0,0}, r1 = (f32x4){0,0,0,0};
    r0 = __builtin_amdgcn_mfma_f32_16x16x32_bf16(af, bm0, r0, 0,0,0);
    r1 = __builtin_amdgcn_mfma_f32_16x16x32_bf16(af, bm1, r1, 0,0,0);
    int kb = rt*16 + quad*4;
    if (mrow >= 5){
      #pragma unroll
      for (int r=0;r<4;++r) sp[(size_t)(kb+r-128)*R_ + mrow] = r0[r];
    } else {
      #pragma unroll
      for (int r=0;r<4;++r) sp[(size_t)(kb+r-128)*R_ + 16 + mrow] = r1[r];
    }
  }
}

// ---------- K3: reduce 72 tile partials -> sal[n][k][21] ----------
__global__ __launch_bounds__(256) void k_salred(const float* __restrict__ salPart,
                                                float* __restrict__ sal){
  int tid = blockIdx.x*256 + threadIdx.x;
  if (tid >= N_*K_*R_) return;
  int n = tid / (K_*R_), i = tid - n*(K_*R_);
  const float* sp = salPart + (size_t)n*NB_*(K_*R_) + i;
  float s = 0.f;
  #pragma unroll 8
  for (int b=0;b<NB_;++b) s += sp[(size_t)b*(K_*R_)];
  sal[tid] = s;
}

// ---------- K4: vlad partials via MFMA. Block = (64-px chunk, n), 512 thr / 8 waves. ----------
// CHV_=36 chunks -> 1152 blocks = 4.5/CU -> full 32 waves/CU (was 2.25 blocks, 18 waves).
__global__ __launch_bounds__(512) void k_vlad(const bf16* __restrict__ xnG,
                                              const unsigned short* __restrict__ a,
                                              const float* __restrict__ sal,
                                              float* __restrict__ vladPart,
                                              float* __restrict__ sumawPart){
  __shared__ float s_sal[K_][R_];                          // 5376 B
  __shared__ __align__(16) unsigned short awL[2][K_][40];  // 10240 B
  __shared__ float s_part[2][K_];                          // 512 B
  int c2 = blockIdx.x, n = blockIdx.y, t = threadIdx.x;
  int p0 = c2*64;
  for (int i=t;i<K_*R_;i+=512) ((float*)s_sal)[i] = sal[(size_t)n*K_*R_ + i];
  __syncthreads();

  // ---- aw = a * (M^T sal): thread = (pixel pxl 0..63, 8-k group kq 0..7) ----
  {
    int pxl = t & 63, kq = t>>6;
    int pbl = pxl>>5, px = pxl&31;
    int p = p0 + pxl;
    int h = p/48, wc = p - h*48;
    bool h1[2], w1[2], h2[4], w2[4];
    #pragma unroll
    for (int i=0;i<2;++i){ h1[i] = (h>=16*i)&&(h<16*i+32); w1[i] = (wc>=16*i)&&(wc<16*i+32); }
    #pragma unroll
    for (int i=0;i<4;++i){ h2[i] = (h>=10*i-1)&&(h<10*i+19); w2[i] = (wc>=10*i-1)&&(wc<10*i+19); }
    const unsigned short* at = a + ((size_t)((n*NB_ + c2*2 + pbl)*32 + px))*K_ + kq*8;
    u16x8 av = *(const u16x8*)at;
    #pragma unroll
    for (int kk=0;kk<8;++kk){
      int k = kq*8 + kk;
      float w = s_sal[k][0];
      #pragma unroll
      for (int i=0;i<2;++i) if (h1[i])
        #pragma unroll
        for (int j=0;j<2;++j) if (w1[j]) w += s_sal[k][1+2*i+j];
      #pragma unroll
      for (int i=0;i<4;++i) if (h2[i])
        #pragma unroll
        for (int j=0;j<4;++j) if (w2[j]) w += s_sal[k][5+4*i+j];
      awL[pbl][k][px] = f2u(u2f(av[kk]) * w);
    }
  }
  __syncthreads();
  // ---- row sums for sum_p(aw) ----
  if (t < 128){
    int k = t&63, qr = t>>6;
    float s = 0.f;
    #pragma unroll 8
    for (int j=0;j<32;++j) s += u2f(awL[qr][k][j]);
    s_part[qr][k] = s;
  }
  __syncthreads();

  // ---- MFMA: wave = (c-quadrant wvc, k-half mh). 8 MFMA/wave. ----
  int wave = t>>6, l = t&63, mrow = l&15, quad = l>>4;
  int wvc = wave&3, mh = wave>>2;
  f32x4 acc[2][2];
  #pragma unroll
  for (int mtl=0;mtl<2;++mtl){ acc[mtl][0] = (f32x4){0,0,0,0}; acc[mtl][1] = (f32x4){0,0,0,0}; }
  const bf16* Gf = xnG + (size_t)(n*CH_ + (c2>>2))*32768 + l*8;  // + ((ks*4+wvc)*2+half)*512
  int ksbase = (c2&3)*2;
  #pragma unroll
  for (int ksl=0;ksl<2;++ksl){
    int ks = ksbase + ksl;
    bf16x8 b0 = *(const bf16x8*)(Gf + ((ks*4+wvc)*2+0)*512);
    bf16x8 b1 = *(const bf16x8*)(Gf + ((ks*4+wvc)*2+1)*512);
    #pragma unroll
    for (int mtl=0;mtl<2;++mtl){
      bf16x8 af = *(const bf16x8*)((const bf16*)&awL[ksl][(mh*2+mtl)*16 + mrow][quad*8]);
      acc[mtl][0] = __builtin_amdgcn_mfma_f32_16x16x32_bf16(af, b0, acc[mtl][0], 0,0,0);
      acc[mtl][1] = __builtin_amdgcn_mfma_f32_16x16x32_bf16(af, b1, acc[mtl][1], 0,0,0);
    }
  }
  float* vp = vladPart + ((size_t)(n*CHV_ + c2))*(K_*C_);
  #pragma unroll
  for (int mtl=0;mtl<2;++mtl){
    #pragma unroll
    for (int ct=0;ct<2;++ct){
      int c = wvc*32 + ct*16 + mrow;
      #pragma unroll
      for (int r=0;r<4;++r){
        int k = (mh*2+mtl)*16 + quad*4 + r;
        vp[k*C_ + c] = acc[mtl][ct][r];
      }
    }
  }
  if (t < K_){
    sumawPart[((size_t)n*CHV_ + c2)*K_ + t] = s_part[0][t] + s_part[1][t];
  }
}

// ---------- K5: parallel chunk reduce + centroid term -> vlad ----------
__global__ __launch_bounds__(256) void k_vred(const float* __restrict__ vladPart,
                                              const float* __restrict__ sumawPart,
                                              const void* __restrict__ cen,
                                              const void* __restrict__ x,
                                              float* __restrict__ vlad){
  int f32 = is_f32((const unsigned short*)x);
  int tid = blockIdx.x*256 + threadIdx.x;       // < N_*K_*C_ = 262144
  int n = tid >> 13;
  int i = tid & 8191;
  int k = i >> 7;
  const float* vp = vladPart + (size_t)n*CHV_*(K_*C_) + i;
  float s = 0.f;
  #pragma unroll 6
  for (int ch=0;ch<CHV_;++ch) s += vp[(size_t)ch*(K_*C_)];
  float sw = 0.f;
  #pragma unroll 6
  for (int ch=0;ch<CHV_;++ch) sw += sumawPart[((size_t)n*CHV_ + ch)*K_ + k];
  float cv = f32 ? ((const float*)cen)[i] : b2f(((const bf16*)cen)[i]);
  vlad[tid] = s - cv*sw;
}

// ---------- K6: intra-norm * cluster_weights, global L2 norm, store ----------
__global__ __launch_bounds__(256) void k_final(const float* __restrict__ vlad,
                                               const void* __restrict__ clw,
                                               const void* __restrict__ x,
                                               void* __restrict__ out){
  __shared__ float s_v[K_*C_];
  __shared__ float s_ssk[K_];
  __shared__ float s_scale[K_];
  __shared__ float s_gs;
  int n = blockIdx.x, t = threadIdx.x;
  int f32 = is_f32((const unsigned short*)x);
  const float* vp = vlad + (size_t)n*K_*C_;
  for (int i=t;i<K_*C_;i+=256) s_v[i] = vp[i];
  __syncthreads();
  int k = t >> 2, q = t & 3;
  float ss = 0.f;
  for (int mm=0;mm<32;++mm){ float v = s_v[k*C_ + q + 4*mm]; ss += v*v; }
  ss += __shfl_down(ss, 2);
  ss += __shfl_down(ss, 1);
  if (q == 0) s_ssk[k] = ss;
  __syncthreads();
  if (t < K_){
    float cw = f32 ? ((const float*)clw)[t] : b2f(((const bf16*)clw)[t]);
    s_scale[t] = cw / fmaxf(sqrtf(s_ssk[t]), 1e-12f);
  }
  __syncthreads();
  if (t == 0){
    float gss = 0.f;
    for (int kk=0;kk<K_;++kk) gss += s_ssk[kk]*s_scale[kk]*s_scale[kk];
    s_gs = 1.f / fmaxf(sqrtf(gss), 1e-12f);
  }
  __syncthreads();
  float gsc = s_gs;
  if (f32){
    float* op = (float*)out + (size_t)n*K_*C_;
    for (int i=t;i<K_*C_;i+=256) op[i] = s_v[i]*s_scale[i>>7]*gsc;
  } else {
    bf16* op = (bf16*)out + (size_t)n*K_*C_;
    for (int i=t;i<K_*C_;i+=256) op[i] = __float2bfloat16(s_v[i]*s_scale[i>>7]*gsc);
  }
}

extern "C" void kernel_launch(void* const* d_in, const int* in_sizes, int n_in,
                              void* d_out, int out_size, void* d_ws, size_t ws_size,
                              hipStream_t stream){
  const void* x   = d_in[0];
  const void* cen = d_in[1];
  const void* cvw = d_in[2];
  const void* csw = d_in[3];
  const void* caw = d_in[4];
  const void* clw = d_in[5];

  char* ws = (char*)d_ws;
  bf16* WallF = (bf16*)ws;             ws += (size_t)M_*C_*2;        // 128 KB
  bf16* xnF   = (bf16*)ws;             ws += (size_t)N_*P_*C_*2;     // 18.87 MB
  bf16* xnG   = (bf16*)ws;             ws += (size_t)N_*C_*P_*2;     // 18.87 MB
  unsigned short* a = (unsigned short*)ws;  ws += (size_t)N_*K_*P_*2; // 9.44 MB (dead after k_vlad)
  float* vlad = (float*)a;                     // overlay: written by k_vred (1 MB)
  float* sal  = (float*)ws;            ws += (size_t)N_*K_*R_*4;     // 0.17 MB
  char* un = ws;
  float* salPart   = (float*)un;               // dead after k_salred
  float* sumawPart = (float*)un;               // overlay: written by k_vlad (294 KB)
  ws += (size_t)N_*NB_*K_*R_*4;                                      // 12.39 MB
  float* vladPart = (float*)ws;        ws += (size_t)N_*CHV_*K_*C_*4; // 37.75 MB

  k_prep  <<<dim3(NBK_ + M_*C_/256), 256, 0, stream>>>(cvw, csw, caw, x, WallF, xnF, xnG);
  k_gemm  <<<dim3(NB_, N_),          512, 0, stream>>>(WallF, xnF, a, salPart);
  k_salred<<<dim3((N_*K_*R_+255)/256), 256, 0, stream>>>(salPart, sal);
  k_vlad  <<<dim3(CHV_, N_),         512, 0, stream>>>(xnG, a, sal, vladPart, sumawPart);
  k_vred  <<<dim3(N_*K_*C_/256),     256, 0, stream>>>(vladPart, sumawPart, cen, x, vlad);
  k_final <<<dim3(N_),               256, 0, stream>>>(vlad, clw, x, d_out);
}

// Round 8
// 149.463 us; speedup vs baseline: 1.1363x; 1.1363x over previous
//
#include <hip/hip_runtime.h>
#include <hip/hip_bf16.h>

#define N_ 32
#define C_ 128
#define H_ 48
#define W_ 48
#define P_ (H_*W_)   // 2304
#define K_ 64
#define S_ 4
#define L_ 3
#define R_ 21
#define NB_ 72       // P_/32 pixel tiles per image
#define M_ 512       // total logit rows
#define CH_ 9        // xnG chunks (256 px each)
#define CHV_ 18      // vlad split-K chunks (128 px each)
#define WBLK_ 576    // k_norm blocks in k_prep (N_*P_/128)
#define MBLK_ 288    // region-mask blocks in k_prep (72*1024/256)

typedef __hip_bfloat16 bf16;
typedef __attribute__((ext_vector_type(8))) short   bf16x8;
typedef __attribute__((ext_vector_type(8))) unsigned short u16x8;
typedef __attribute__((ext_vector_type(4))) unsigned short u16x4;
typedef __attribute__((ext_vector_type(4))) float   f32x4;

__device__ __forceinline__ float b2f(bf16 v){ return __bfloat162float(v); }
__device__ __forceinline__ float u2f(unsigned short u){
  union { unsigned i; float f; } v; v.i = ((unsigned)u) << 16; return v.f;
}
__device__ __forceinline__ unsigned short f2u(float f){
  bf16 h = __float2bfloat16(f);
  return *(unsigned short*)&h;
}

// wave-uniform dtype probe: 1 if x is fp32, 0 if bf16 (reads fixed 1024-elem window).
__device__ __forceinline__ int is_f32(const unsigned short* __restrict__ xb){
  int lane = threadIdx.x & 63;
  int w = 0;
  #pragma unroll
  for (int i=0;i<16;++i){
    int e = (xb[lane*16 + i] >> 7) & 0xFF;
    w += (e >= 0x8E) ? 1 : 0;
  }
  unsigned long long b = __ballot(w > 0);
  return __popcll(b) > 32;
}

// region membership for global region index r (0..20) at pixel (h,w); bf16 1.0/0.0 bits
__device__ __forceinline__ unsigned short region_bit(int r, int h, int w){
  bool m;
  if (r == 0){
    m = true;
  } else if (r < 5){
    int q = r-1, i = q>>1, j = q&1;
    m = (h>=16*i)&&(h<16*i+32)&&(w>=16*j)&&(w<16*j+32);
  } else if (r < 21){
    int q = r-5, i = q>>2, j = q&3;
    m = (h>=10*i-1)&&(h<10*i+19)&&(w>=10*j-1)&&(w<10*j+19);
  } else {
    m = false;
  }
  return m ? (unsigned short)0x3F80 : (unsigned short)0;
}

// ---------- K_A: fused k_wall + k_norm + region-mask fragment table ----------
// blocks [0,WBLK_)              : 128-px L2-norm -> xnF/xnG (round-6 proven version)
// blocks [WBLK_, WBLK_+256)     : WallF build
// blocks [WBLK_+256, +MBLK_)    : bmF[pb][tile01][lane][8] region-mask B-frags (bf16 bits)
__global__ __launch_bounds__(256) void k_prep(const void* __restrict__ cvw, const void* __restrict__ csw,
                                              const void* __restrict__ caw, const void* __restrict__ x,
                                              bf16* __restrict__ WallF, bf16* __restrict__ xnF,
                                              bf16* __restrict__ xnG, unsigned short* __restrict__ bmF){
  int bid = blockIdx.x, t = threadIdx.x;
  if (bid >= WBLK_ + 256){
    // ---- region-mask fragments: i = ((pb*2+tl)*64+lane)*8 + j ----
    int i = (bid - WBLK_ - 256)*256 + t;           // 0..73727
    int j = i&7, lane = (i>>3)&63, tl = (i>>9)&1, pb = i>>10;
    int mrow = lane&15, quad = lane>>4;
    int r = tl*16 + mrow;
    int p = pb*32 + quad*8 + j;
    int h = p/48, wc = p - h*48;
    bmF[i] = (r < R_) ? region_bit(r, h, wc) : (unsigned short)0;
    return;
  }
  int f32 = is_f32((const unsigned short*)x);
  if (bid >= WBLK_){
    // ---- WallF build: frag f = ((rt*4+ks)*64 + lane)*8 + j ----
    int i = (bid - WBLK_)*256 + t;                 // 0..65535
    int j = i&7, lane = (i>>3)&63, ks = (i>>9)&3, rt = (i>>11)&31;
    int row = rt*16 + (lane&15);
    int c   = ks*32 + ((lane>>4)&3)*8 + j;
    int s = row*C_ + c;
    float v;
    if (s < 8192)       v = f32 ? ((const float*)cvw)[s]        : b2f(((const bf16*)cvw)[s]);
    else if (s < 40960) v = f32 ? ((const float*)csw)[s-8192]   : b2f(((const bf16*)csw)[s-8192]);
    else                v = f32 ? ((const float*)caw)[s-40960]  : b2f(((const bf16*)caw)[s-40960]);
    WallF[i] = __float2bfloat16(v);
    return;
  }

  // ---- k_norm role (round-6 proven) ----
  __shared__ float sred[2][128];
  __shared__ __align__(16) unsigned short tile[128][136];   // 34816 B, 16B-aligned rows
  int n = bid / (P_/128), tb = bid % (P_/128);
  int p0 = tb*128;
  int px = t&127, chh = t>>7, c0 = chh*64;

  float vals[64];
  float ss = 0.f;
  if (f32){
    const float* xb = (const float*)x + ((size_t)n*C_ + c0)*P_ + p0 + px;
    #pragma unroll
    for (int j=0;j<64;++j){ float v = xb[(size_t)j*P_]; vals[j] = v; ss += v*v; }
  } else {
    const unsigned short* xb = (const unsigned short*)x + ((size_t)n*C_ + c0)*P_ + p0 + px;
    #pragma unroll
    for (int j=0;j<64;++j){ float v = u2f(xb[(size_t)j*P_]); vals[j] = v; ss += v*v; }
  }
  sred[chh][px] = ss;
  __syncthreads();
  float invn = 1.f / fmaxf(sqrtf(sred[0][px] + sred[1][px]), 1e-12f);
  unsigned short nv[64];
  #pragma unroll
  for (int j=0;j<64;++j) nv[j] = f2u(vals[j]*invn);

  // ---- phase A: tile[c][px] ----
  #pragma unroll
  for (int j=0;j<64;++j) tile[c0+j][px] = nv[j];
  __syncthreads();
  // emit xnG (chunk ch = tb>>1 covers 256 px; this block is half hb)
  {
    int ch = tb>>1, hb = tb&1;
    size_t gbase = ((size_t)(n*CH_ + ch)*8 + hb*4)*512;
    u16x8* out = (u16x8*)xnG;
    #pragma unroll
    for (int it=0;it<8;++it){
      int o2 = t + it*256;
      int lane = o2&63, half = (o2>>6)&1, wvv = (o2>>7)&3, ksl = (o2>>9)&3;
      int c  = wvv*32 + half*16 + (lane&15);
      int pl = ksl*32 + ((lane>>4)&3)*8;
      out[gbase + o2] = *(const u16x8*)&tile[c][pl];
    }
  }
  __syncthreads();
  // ---- phase B: reuse tile as [px][c] ----
  #pragma unroll
  for (int j8=0;j8<8;++j8)
    *(u16x8*)&tile[px][c0 + j8*8] = *(const u16x8*)&nv[j8*8];
  __syncthreads();
  // emit xnF (4 gemm-tiles pb = tb*4 + pbl)
  {
    size_t fbase = (size_t)(n*NB_ + tb*4)*512;
    u16x8* out = (u16x8*)xnF;
    #pragma unroll
    for (int it=0;it<8;++it){
      int o = t + it*256;
      int lane = o&63, half = (o>>6)&1, ks = (o>>7)&3, pbl = (o>>9)&3;
      int pxr = pbl*32 + half*16 + (lane&15);
      int cc  = ks*32 + ((lane>>4)&3)*8;
      out[fbase + o] = *(const u16x8*)&tile[pxr][cc];
    }
  }
}

// ---------- K_B: fused 512-row MFMA GEMM + softmax + MFMA region sums ----------
// grid (NB_=72, N_=32), 512 thr / 8 waves; wave w owns rows [w*64, w*64+64).
// Round-8: region masks read from precomputed bmF (1-2 b128 loads, was ~200 VALU);
// all index math 32-bit.
__global__ __launch_bounds__(512, 4) void k_gemm(const bf16* __restrict__ WallF,
                                                 const bf16* __restrict__ xnF,
                                                 const unsigned short* __restrict__ bmF,
                                                 unsigned short* __restrict__ a,
                                                 float* __restrict__ salPart){
  __shared__ __align__(16) unsigned short ldsU[320][40];    // 25600 B
  __shared__ __align__(16) unsigned short appS[192][40];    // 15360 B
  int n = blockIdx.y, pb = blockIdx.x;
  int t = threadIdx.x, w = t>>6, l = t&63;
  int mrow = l&15, quad = l>>4;

  const bf16* Af = WallF + (w*4*4)*512 + l*8;              // + (rtl*4+ks)*512
  const bf16* Bf = xnF + (size_t)(n*NB_ + pb)*4096 + l*8;  // + (ks*2+half)*512

  f32x4 acc[4][2];
  #pragma unroll
  for (int rtl=0;rtl<4;++rtl){ acc[rtl][0] = (f32x4){0,0,0,0}; acc[rtl][1] = (f32x4){0,0,0,0}; }

  #pragma unroll
  for (int ks=0;ks<4;++ks){
    bf16x8 b0 = *(const bf16x8*)(Bf + (ks*2+0)*512);
    bf16x8 b1 = *(const bf16x8*)(Bf + (ks*2+1)*512);
    #pragma unroll
    for (int rtl=0;rtl<4;++rtl){
      bf16x8 af = *(const bf16x8*)(Af + (rtl*4+ks)*512);
      acc[rtl][0] = __builtin_amdgcn_mfma_f32_16x16x32_bf16(af, b0, acc[rtl][0], 0,0,0);
      acc[rtl][1] = __builtin_amdgcn_mfma_f32_16x16x32_bf16(af, b1, acc[rtl][1], 0,0,0);
    }
  }

  // C/D: col = lane&15, row = quad*4 + reg. Wave-uniform routing by row range.
  #pragma unroll
  for (int rtl=0;rtl<4;++rtl){
    int row0 = w*64 + rtl*16;
    if (row0 < 64){                       // scores, k-major
      #pragma unroll
      for (int ct=0;ct<2;++ct)
        #pragma unroll
        for (int r=0;r<4;++r)
          ldsU[row0 + quad*4 + r][ct*16 + mrow] = f2u(acc[rtl][ct][r]);
    } else if (row0 < 320){               // shadows, s-major: row 64 + s*64 + k
      #pragma unroll
      for (int ct=0;ct<2;++ct)
        #pragma unroll
        for (int r=0;r<4;++r){
          int sr = row0 + quad*4 + r - 64;                  // = k*4 + s
          ldsU[64 + (sr&3)*64 + (sr>>2)][ct*16 + mrow] = f2u(acc[rtl][ct][r]);
        }
    } else {                              // app rows, relu'd, direct to appS
      int ar0 = row0 - 320 + quad*4;
      #pragma unroll
      for (int ct=0;ct<2;++ct)
        #pragma unroll
        for (int r=0;r<4;++r)
          appS[ar0 + r][ct*16 + mrow] = f2u(fmaxf(acc[rtl][ct][r], 0.f));
    }
  }
  __syncthreads();   // the only barrier

  // issue mask-frag loads early; they hide under softmax (independent of LDS)
  const unsigned short* bmp = bmF + pb*1024 + l*8;
  bf16x8 bm0 = *(const bf16x8*)bmp;
  bf16x8 bm1;
  if (w >= 4) bm1 = *(const bf16x8*)(bmp + 512);

  // ---- softmax: lane = k, wave w = pixel-group (4 px). 5 x ds_read_b64, read-only. ----
  {
    u16x4 s4  = *(const u16x4*)&ldsU[l      ][w*4];
    u16x4 h0v = *(const u16x4*)&ldsU[64  + l][w*4];
    u16x4 h1v = *(const u16x4*)&ldsU[128 + l][w*4];
    u16x4 h2v = *(const u16x4*)&ldsU[192 + l][w*4];
    u16x4 h3v = *(const u16x4*)&ldsU[256 + l][w*4];
    float ez[4], Zr[4];
    #pragma unroll
    for (int j=0;j<4;++j){ ez[j] = __expf(u2f((unsigned short)s4[j])); Zr[j] = ez[j]; }
    #pragma unroll
    for (int st=1; st<64; st<<=1){
      #pragma unroll
      for (int j=0;j<4;++j) Zr[j] += __shfl_xor(Zr[j], st);
    }
    int abase = (n*NB_ + pb)*2048 + w*256 + l;
    #pragma unroll
    for (int j=0;j<4;++j){
      float e0 = ez[j];
      float den = e0 + __expf(u2f((unsigned short)h0v[j]))
                     + __expf(u2f((unsigned short)h1v[j]))
                     + __expf(u2f((unsigned short)h2v[j]))
                     + __expf(u2f((unsigned short)h3v[j]));
      a[abase + j*64] = f2u(__fdividef(e0*e0, Zr[j]*den));
    }
  }

  // ---- region sums via MFMA: salPart[tile][k][r] = sum_p app[k][p] * M[r][p] ----
  float* sp = salPart + (n*NB_ + pb)*(K_*R_);
  if (w < 4){
    #pragma unroll
    for (int i=0;i<2;++i){
      int rt = w*2 + i;
      bf16x8 af = *(const bf16x8*)&appS[rt*16 + mrow][quad*8];
      f32x4 r0 = (f32x4){0,0,0,0};
      r0 = __builtin_amdgcn_mfma_f32_16x16x32_bf16(af, bm0, r0, 0,0,0);
      int kb = rt*16 + quad*4;
      if (rt < 4){                       // level0: region col 0 only
        if (mrow == 0){
          #pragma unroll
          for (int r=0;r<4;++r) sp[(kb+r)*R_] = r0[r];
        }
      } else {                           // level1: cols 1..4
        if (mrow >= 1 && mrow <= 4){
          #pragma unroll
          for (int r=0;r<4;++r) sp[(kb+r-64)*R_ + mrow] = r0[r];
        }
      }
    }
  } else {
    int rt = 8 + (w-4);                  // level2: cols 5..20
    bf16x8 af = *(const bf16x8*)&appS[rt*16 + mrow][quad*8];
    f32x4 r0 = (f32x4){0,0,0,0}, r1 = (f32x4){0,0,0,0};
    r0 = __builtin_amdgcn_mfma_f32_16x16x32_bf16(af, bm0, r0, 0,0,0);
    r1 = __builtin_amdgcn_mfma_f32_16x16x32_bf16(af, bm1, r1, 0,0,0);
    int kb = rt*16 + quad*4;
    if (mrow >= 5){
      #pragma unroll
      for (int r=0;r<4;++r) sp[(kb+r-128)*R_ + mrow] = r0[r];
    } else {
      #pragma unroll
      for (int r=0;r<4;++r) sp[(kb+r-128)*R_ + 16 + mrow] = r1[r];
    }
  }
}

// ---------- K3: reduce 72 tile partials -> sal[n][k][21] ----------
__global__ __launch_bounds__(256) void k_salred(const float* __restrict__ salPart,
                                                float* __restrict__ sal){
  int tid = blockIdx.x*256 + threadIdx.x;
  if (tid >= N_*K_*R_) return;
  int n = tid / (K_*R_), i = tid - n*(K_*R_);
  const float* sp = salPart + (size_t)n*NB_*(K_*R_) + i;
  float s = 0.f;
  #pragma unroll 8
  for (int b=0;b<NB_;++b) s += sp[(size_t)b*(K_*R_)];
  sal[tid] = s;
}

// ---------- K4: vlad partials via MFMA. Block = (128-px chunk, n), 512 thr / 8 waves. ----------
__global__ __launch_bounds__(512) void k_vlad(const bf16* __restrict__ xnG,
                                              const unsigned short* __restrict__ a,
                                              const float* __restrict__ sal,
                                              float* __restrict__ vladPart,
                                              float* __restrict__ sumawPart){
  __shared__ float s_sal[K_][R_];                          // 5376 B
  __shared__ __align__(16) unsigned short awL[4][K_][40];  // 20480 B
  __shared__ float s_part[4][K_];                          // 1024 B
  int c2 = blockIdx.x, n = blockIdx.y, t = threadIdx.x;
  int p0 = c2*128;
  for (int i=t;i<K_*R_;i+=512) ((float*)s_sal)[i] = sal[(size_t)n*K_*R_ + i];
  __syncthreads();

  // ---- aw = a * (M^T sal) for this chunk: thread = (pixel pxl, 16-k group kq) ----
  {
    int pxl = t & 127, kq = t>>7;
    int pbl = pxl>>5, px = pxl&31;
    int p = p0 + pxl;
    int h = p/48, wc = p - h*48;
    bool h1[2], w1[2], h2[4], w2[4];
    #pragma unroll
    for (int i=0;i<2;++i){ h1[i] = (h>=16*i)&&(h<16*i+32); w1[i] = (wc>=16*i)&&(wc<16*i+32); }
    #pragma unroll
    for (int i=0;i<4;++i){ h2[i] = (h>=10*i-1)&&(h<10*i+19); w2[i] = (wc>=10*i-1)&&(wc<10*i+19); }
    const unsigned short* at = a + ((size_t)((n*NB_ + c2*4 + pbl)*32 + px))*K_ + kq*16;
    u16x8 av[2];
    av[0] = *(const u16x8*)at;
    av[1] = *(const u16x8*)(at + 8);
    #pragma unroll
    for (int kk=0;kk<16;++kk){
      int k = kq*16 + kk;
      float w = s_sal[k][0];
      #pragma unroll
      for (int i=0;i<2;++i) if (h1[i])
        #pragma unroll
        for (int j=0;j<2;++j) if (w1[j]) w += s_sal[k][1+2*i+j];
      #pragma unroll
      for (int i=0;i<4;++i) if (h2[i])
        #pragma unroll
        for (int j=0;j<4;++j) if (w2[j]) w += s_sal[k][5+4*i+j];
      awL[pbl][k][px] = f2u(u2f(av[kk>>3][kk&7]) * w);
    }
  }
  __syncthreads();
  // ---- row sums for sum_p(aw) ----
  if (t < 256){
    int k = t&63, qr = t>>6;
    float s = 0.f;
    #pragma unroll 8
    for (int j=0;j<32;++j) s += u2f(awL[qr][k][j]);
    s_part[qr][k] = s;
  }
  __syncthreads();

  // ---- MFMA: wave = (c-quadrant wvc, k-half mh). 16 MFMA/wave. ----
  int wave = t>>6, l = t&63, mrow = l&15, quad = l>>4;
  int wvc = wave&3, mh = wave>>2;
  f32x4 acc[2][2];
  #pragma unroll
  for (int mtl=0;mtl<2;++mtl){ acc[mtl][0] = (f32x4){0,0,0,0}; acc[mtl][1] = (f32x4){0,0,0,0}; }
  const bf16* Gf = xnG + (size_t)(n*CH_ + (c2>>1))*32768 + l*8;  // + ((ks*4+wvc)*2+half)*512
  int ksbase = (c2&1)*4;
  #pragma unroll
  for (int ksl=0;ksl<4;++ksl){
    int ks = ksbase + ksl;
    bf16x8 b0 = *(const bf16x8*)(Gf + ((ks*4+wvc)*2+0)*512);
    bf16x8 b1 = *(const bf16x8*)(Gf + ((ks*4+wvc)*2+1)*512);
    #pragma unroll
    for (int mtl=0;mtl<2;++mtl){
      bf16x8 af = *(const bf16x8*)((const bf16*)&awL[ksl][(mh*2+mtl)*16 + mrow][quad*8]);
      acc[mtl][0] = __builtin_amdgcn_mfma_f32_16x16x32_bf16(af, b0, acc[mtl][0], 0,0,0);
      acc[mtl][1] = __builtin_amdgcn_mfma_f32_16x16x32_bf16(af, b1, acc[mtl][1], 0,0,0);
    }
  }
  float* vp = vladPart + ((size_t)(n*CHV_ + c2))*(K_*C_);
  #pragma unroll
  for (int mtl=0;mtl<2;++mtl){
    #pragma unroll
    for (int ct=0;ct<2;++ct){
      int c = wvc*32 + ct*16 + mrow;
      #pragma unroll
      for (int r=0;r<4;++r){
        int k = (mh*2+mtl)*16 + quad*4 + r;
        vp[k*C_ + c] = acc[mtl][ct][r];
      }
    }
  }
  if (t < K_){
    float s = s_part[0][t] + s_part[1][t] + s_part[2][t] + s_part[3][t];
    sumawPart[((size_t)n*CHV_ + c2)*K_ + t] = s;
  }
}

// ---------- K5: fused chunk-reduce + centroid term + intra/global norms + output ----------
// One block per image, 1024 threads. No intermediate vlad buffer.
__global__ __launch_bounds__(1024) void k_vfinal(const float* __restrict__ vladPart,
                                                 const float* __restrict__ sumawPart,
                                                 const void* __restrict__ cen,
                                                 const void* __restrict__ clw,
                                                 const void* __restrict__ x,
                                                 void* __restrict__ out){
  __shared__ float s_v[K_*C_];          // 32768 B
  __shared__ float s_sw[K_];
  __shared__ float s_ssk[K_];
  __shared__ float s_scale[K_];
  __shared__ float s_gs;
  int n = blockIdx.x, t = threadIdx.x;
  int f32 = is_f32((const unsigned short*)x);

  if (t < K_){
    float sw = 0.f;
    #pragma unroll
    for (int ch=0;ch<CHV_;++ch) sw += sumawPart[((size_t)n*CHV_ + ch)*K_ + t];
    s_sw[t] = sw;
  }
  __syncthreads();
  {
    const float* vpn = vladPart + (size_t)n*CHV_*(K_*C_);
    for (int i=t;i<K_*C_;i+=1024){
      float s = 0.f;
      #pragma unroll
      for (int ch=0;ch<CHV_;++ch) s += vpn[(size_t)ch*(K_*C_) + i];
      float cv = f32 ? ((const float*)cen)[i] : b2f(((const bf16*)cen)[i]);
      s_v[i] = s - cv*s_sw[i>>7];
    }
  }
  __syncthreads();
  {
    int k = t>>4, q = t&15;               // 16 threads per cluster, 8 elems each
    float ss = 0.f;
    #pragma unroll
    for (int mm=0;mm<8;++mm){ float v = s_v[k*C_ + q + 16*mm]; ss += v*v; }
    ss += __shfl_down(ss, 8);
    ss += __shfl_down(ss, 4);
    ss += __shfl_down(ss, 2);
    ss += __shfl_down(ss, 1);
    if (q == 0) s_ssk[k] = ss;
  }
  __syncthreads();
  if (t < K_){
    float cw = f32 ? ((const float*)clw)[t] : b2f(((const bf16*)clw)[t]);
    s_scale[t] = cw / fmaxf(sqrtf(s_ssk[t]), 1e-12f);
  }
  __syncthreads();
  if (t == 0){
    float gss = 0.f;
    for (int kk=0;kk<K_;++kk) gss += s_ssk[kk]*s_scale[kk]*s_scale[kk];
    s_gs = 1.f / fmaxf(sqrtf(gss), 1e-12f);
  }
  __syncthreads();
  float gsc = s_gs;
  if (f32){
    float* op = (float*)out + (size_t)n*K_*C_;
    for (int i=t;i<K_*C_;i+=1024) op[i] = s_v[i]*s_scale[i>>7]*gsc;
  } else {
    bf16* op = (bf16*)out + (size_t)n*K_*C_;
    for (int i=t;i<K_*C_;i+=1024) op[i] = __float2bfloat16(s_v[i]*s_scale[i>>7]*gsc);
  }
}

extern "C" void kernel_launch(void* const* d_in, const int* in_sizes, int n_in,
                              void* d_out, int out_size, void* d_ws, size_t ws_size,
                              hipStream_t stream){
  const void* x   = d_in[0];
  const void* cen = d_in[1];
  const void* cvw = d_in[2];
  const void* csw = d_in[3];
  const void* caw = d_in[4];
  const void* clw = d_in[5];

  char* ws = (char*)d_ws;
  bf16* WallF = (bf16*)ws;             ws += (size_t)M_*C_*2;        // 128 KB
  bf16* xnF   = (bf16*)ws;             ws += (size_t)N_*P_*C_*2;     // 18.87 MB
  bf16* xnG   = (bf16*)ws;             ws += (size_t)N_*C_*P_*2;     // 18.87 MB
  unsigned short* a = (unsigned short*)ws;  ws += (size_t)N_*K_*P_*2; // 9.44 MB
  float* sal  = (float*)ws;            ws += (size_t)N_*K_*R_*4;     // 0.17 MB
  char* un = ws;
  float* salPart   = (float*)un;               // dead after k_salred
  float* sumawPart = (float*)un;               // overlay: written by k_vlad (147 KB)
  ws += (size_t)N_*NB_*K_*R_*4;                                      // 12.39 MB
  unsigned short* bmF = (unsigned short*)ws; ws += (size_t)NB_*2*512*2; // 147 KB
  // vladPart overlays xnF (dead after k_gemm); N_*CHV_*K_*C_*4 == N_*P_*C_*2 exactly.
  float* vladPart = (float*)xnF;

  k_prep  <<<dim3(WBLK_ + M_*C_/256 + MBLK_), 256, 0, stream>>>(cvw, csw, caw, x,
                                                                WallF, xnF, xnG, bmF);
  k_gemm  <<<dim3(NB_, N_),           512, 0, stream>>>(WallF, xnF, bmF, a, salPart);
  k_salred<<<dim3((N_*K_*R_+255)/256), 256, 0, stream>>>(salPart, sal);
  k_vlad  <<<dim3(CHV_, N_),          512, 0, stream>>>(xnG, a, sal, vladPart, sumawPart);
  k_vfinal<<<dim3(N_),               1024, 0, stream>>>(vladPart, sumawPart, cen, clw, x, d_out);
}

// Round 9
// 145.706 us; speedup vs baseline: 1.1656x; 1.0258x over previous
//
#include <hip/hip_runtime.h>
#include <hip/hip_bf16.h>

#define N_ 32
#define C_ 128
#define H_ 48
#define W_ 48
#define P_ (H_*W_)   // 2304
#define K_ 64
#define S_ 4
#define L_ 3
#define R_ 21
#define NB_ 72       // P_/32 pixel tiles per image
#define M_ 512       // total logit rows
#define CH_ 9        // xnG chunks (256 px each)
#define CHV_ 18      // vlad split-K chunks (128 px each)
#define WBLK_ 576    // k_norm blocks in k_prep (N_*P_/128)
#define MBLK_ 288    // region-mask blocks in k_prep (72*1024/256)

typedef __hip_bfloat16 bf16;
typedef __attribute__((ext_vector_type(8))) short   bf16x8;
typedef __attribute__((ext_vector_type(8))) unsigned short u16x8;
typedef __attribute__((ext_vector_type(4))) unsigned short u16x4;
typedef __attribute__((ext_vector_type(4))) float   f32x4;

__device__ __forceinline__ float b2f(bf16 v){ return __bfloat162float(v); }
__device__ __forceinline__ float u2f(unsigned short u){
  union { unsigned i; float f; } v; v.i = ((unsigned)u) << 16; return v.f;
}
__device__ __forceinline__ unsigned short f2u(float f){
  bf16 h = __float2bfloat16(f);
  return *(unsigned short*)&h;
}

// wave-uniform dtype probe: 1 if x is fp32, 0 if bf16 (reads fixed 1024-elem window).
__device__ __forceinline__ int is_f32(const unsigned short* __restrict__ xb){
  int lane = threadIdx.x & 63;
  int w = 0;
  #pragma unroll
  for (int i=0;i<16;++i){
    int e = (xb[lane*16 + i] >> 7) & 0xFF;
    w += (e >= 0x8E) ? 1 : 0;
  }
  unsigned long long b = __ballot(w > 0);
  return __popcll(b) > 32;
}

// region membership for global region index r (0..20) at pixel (h,w); bf16 1.0/0.0 bits
__device__ __forceinline__ unsigned short region_bit(int r, int h, int w){
  bool m;
  if (r == 0){
    m = true;
  } else if (r < 5){
    int q = r-1, i = q>>1, j = q&1;
    m = (h>=16*i)&&(h<16*i+32)&&(w>=16*j)&&(w<16*j+32);
  } else if (r < 21){
    int q = r-5, i = q>>2, j = q&3;
    m = (h>=10*i-1)&&(h<10*i+19)&&(w>=10*j-1)&&(w<10*j+19);
  } else {
    m = false;
  }
  return m ? (unsigned short)0x3F80 : (unsigned short)0;
}

// ---------- K_A: fused k_wall + k_norm + region-mask fragment table ----------
// blocks [0,WBLK_)              : 128-px L2-norm -> xnF/xnG (round-6 proven version)
// blocks [WBLK_, WBLK_+256)     : WallF build
// blocks [WBLK_+256, +MBLK_)    : bmF[pb][tile01][lane][8] region-mask B-frags (bf16 bits)
__global__ __launch_bounds__(256) void k_prep(const void* __restrict__ cvw, const void* __restrict__ csw,
                                              const void* __restrict__ caw, const void* __restrict__ x,
                                              bf16* __restrict__ WallF, bf16* __restrict__ xnF,
                                              bf16* __restrict__ xnG, unsigned short* __restrict__ bmF){
  int bid = blockIdx.x, t = threadIdx.x;
  if (bid >= WBLK_ + 256){
    // ---- region-mask fragments: i = ((pb*2+tl)*64+lane)*8 + j ----
    int i = (bid - WBLK_ - 256)*256 + t;           // 0..73727
    int j = i&7, lane = (i>>3)&63, tl = (i>>9)&1, pb = i>>10;
    int mrow = lane&15, quad = lane>>4;
    int r = tl*16 + mrow;
    int p = pb*32 + quad*8 + j;
    int h = p/48, wc = p - h*48;
    bmF[i] = (r < R_) ? region_bit(r, h, wc) : (unsigned short)0;
    return;
  }
  int f32 = is_f32((const unsigned short*)x);
  if (bid >= WBLK_){
    // ---- WallF build: frag f = ((rt*4+ks)*64 + lane)*8 + j ----
    int i = (bid - WBLK_)*256 + t;                 // 0..65535
    int j = i&7, lane = (i>>3)&63, ks = (i>>9)&3, rt = (i>>11)&31;
    int row = rt*16 + (lane&15);
    int c   = ks*32 + ((lane>>4)&3)*8 + j;
    int s = row*C_ + c;
    float v;
    if (s < 8192)       v = f32 ? ((const float*)cvw)[s]        : b2f(((const bf16*)cvw)[s]);
    else if (s < 40960) v = f32 ? ((const float*)csw)[s-8192]   : b2f(((const bf16*)csw)[s-8192]);
    else                v = f32 ? ((const float*)caw)[s-40960]  : b2f(((const bf16*)caw)[s-40960]);
    WallF[i] = __float2bfloat16(v);
    return;
  }

  // ---- k_norm role (round-6 proven) ----
  __shared__ float sred[2][128];
  __shared__ __align__(16) unsigned short tile[128][136];   // 34816 B, 16B-aligned rows
  int n = bid / (P_/128), tb = bid % (P_/128);
  int p0 = tb*128;
  int px = t&127, chh = t>>7, c0 = chh*64;

  float vals[64];
  float ss = 0.f;
  if (f32){
    const float* xb = (const float*)x + ((size_t)n*C_ + c0)*P_ + p0 + px;
    #pragma unroll
    for (int j=0;j<64;++j){ float v = xb[(size_t)j*P_]; vals[j] = v; ss += v*v; }
  } else {
    const unsigned short* xb = (const unsigned short*)x + ((size_t)n*C_ + c0)*P_ + p0 + px;
    #pragma unroll
    for (int j=0;j<64;++j){ float v = u2f(xb[(size_t)j*P_]); vals[j] = v; ss += v*v; }
  }
  sred[chh][px] = ss;
  __syncthreads();
  float invn = 1.f / fmaxf(sqrtf(sred[0][px] + sred[1][px]), 1e-12f);
  unsigned short nv[64];
  #pragma unroll
  for (int j=0;j<64;++j) nv[j] = f2u(vals[j]*invn);

  // ---- phase A: tile[c][px] ----
  #pragma unroll
  for (int j=0;j<64;++j) tile[c0+j][px] = nv[j];
  __syncthreads();
  // emit xnG (chunk ch = tb>>1 covers 256 px; this block is half hb)
  {
    int ch = tb>>1, hb = tb&1;
    size_t gbase = ((size_t)(n*CH_ + ch)*8 + hb*4)*512;
    u16x8* out = (u16x8*)xnG;
    #pragma unroll
    for (int it=0;it<8;++it){
      int o2 = t + it*256;
      int lane = o2&63, half = (o2>>6)&1, wvv = (o2>>7)&3, ksl = (o2>>9)&3;
      int c  = wvv*32 + half*16 + (lane&15);
      int pl = ksl*32 + ((lane>>4)&3)*8;
      out[gbase + o2] = *(const u16x8*)&tile[c][pl];
    }
  }
  __syncthreads();
  // ---- phase B: reuse tile as [px][c] ----
  #pragma unroll
  for (int j8=0;j8<8;++j8)
    *(u16x8*)&tile[px][c0 + j8*8] = *(const u16x8*)&nv[j8*8];
  __syncthreads();
  // emit xnF (4 gemm-tiles pb = tb*4 + pbl)
  {
    size_t fbase = (size_t)(n*NB_ + tb*4)*512;
    u16x8* out = (u16x8*)xnF;
    #pragma unroll
    for (int it=0;it<8;++it){
      int o = t + it*256;
      int lane = o&63, half = (o>>6)&1, ks = (o>>7)&3, pbl = (o>>9)&3;
      int pxr = pbl*32 + half*16 + (lane&15);
      int cc  = ks*32 + ((lane>>4)&3)*8;
      out[fbase + o] = *(const u16x8*)&tile[pxr][cc];
    }
  }
}

// ---------- K_B: fused 512-row MFMA GEMM + softmax + MFMA region sums ----------
// grid (NB_=72, N_=32), 512 thr / 8 waves; wave w owns rows [w*64, w*64+64).
// Round-9: px-major logit LDS (ldsP[px][328]: scores [px][k], shadows [px][64+k*4+s]).
// C/D lands as b64 vector writes (8/thread, was 32 scalar); softmax reads b64+2xb128
// contiguously; Z-reduce is a 4-step 16-lane shuffle (was 6x4); a-store is one dwordx2.
__global__ __launch_bounds__(512, 4) void k_gemm(const bf16* __restrict__ WallF,
                                                 const bf16* __restrict__ xnF,
                                                 const unsigned short* __restrict__ bmF,
                                                 unsigned short* __restrict__ a,
                                                 float* __restrict__ salPart){
  __shared__ __align__(16) unsigned short ldsP[32][328];    // 20992 B (656B rows, 16B-mult)
  __shared__ __align__(16) unsigned short appS[192][40];    // 15360 B
  int n = blockIdx.y, pb = blockIdx.x;
  int t = threadIdx.x, w = t>>6, l = t&63;
  int mrow = l&15, quad = l>>4;

  const bf16* Af = WallF + (w*16)*512 + l*8;               // + (rtl*4+ks)*512
  const bf16* Bf = xnF + (size_t)(n*NB_ + pb)*4096 + l*8;  // + (ks*2+half)*512

  f32x4 acc[4][2];
  #pragma unroll
  for (int rtl=0;rtl<4;++rtl){ acc[rtl][0] = (f32x4){0,0,0,0}; acc[rtl][1] = (f32x4){0,0,0,0}; }

  #pragma unroll
  for (int ks=0;ks<4;++ks){
    bf16x8 b0 = *(const bf16x8*)(Bf + (ks*2+0)*512);
    bf16x8 b1 = *(const bf16x8*)(Bf + (ks*2+1)*512);
    #pragma unroll
    for (int rtl=0;rtl<4;++rtl){
      bf16x8 af = *(const bf16x8*)(Af + (rtl*4+ks)*512);
      acc[rtl][0] = __builtin_amdgcn_mfma_f32_16x16x32_bf16(af, b0, acc[rtl][0], 0,0,0);
      acc[rtl][1] = __builtin_amdgcn_mfma_f32_16x16x32_bf16(af, b1, acc[rtl][1], 0,0,0);
    }
  }

  // C/D: col = lane&15 (px), row = quad*4 + reg (4 consecutive rows -> packed b64).
  if (w == 0){
    // scores rows 0..63: k = rtl*16 + quad*4 + r -> ldsP[px][k..k+3]
    #pragma unroll
    for (int rtl=0;rtl<4;++rtl)
      #pragma unroll
      for (int ct=0;ct<2;++ct){
        uint2 pk;
        pk.x = (unsigned)f2u(acc[rtl][ct][0]) | ((unsigned)f2u(acc[rtl][ct][1]) << 16);
        pk.y = (unsigned)f2u(acc[rtl][ct][2]) | ((unsigned)f2u(acc[rtl][ct][3]) << 16);
        *(uint2*)&ldsP[ct*16 + mrow][rtl*16 + quad*4] = pk;
      }
  } else if (w < 5){
    // shadow rows: sr = (w-1)*64 + rtl*16 + quad*4 + r = k*4 + s with
    // k = (w-1)*16 + rtl*4 + quad (const over r), s = r -> ldsP[px][64+k*4 .. +3]
    int kb = (w-1)*16;
    #pragma unroll
    for (int rtl=0;rtl<4;++rtl)
      #pragma unroll
      for (int ct=0;ct<2;++ct){
        uint2 pk;
        pk.x = (unsigned)f2u(acc[rtl][ct][0]) | ((unsigned)f2u(acc[rtl][ct][1]) << 16);
        pk.y = (unsigned)f2u(acc[rtl][ct][2]) | ((unsigned)f2u(acc[rtl][ct][3]) << 16);
        *(uint2*)&ldsP[ct*16 + mrow][64 + (kb + rtl*4 + quad)*4] = pk;
      }
  } else {
    // app rows 320..511: relu'd, k-major appS (region MFMA A-frag layout)
    #pragma unroll
    for (int rtl=0;rtl<4;++rtl){
      int ar0 = (w-5)*64 + rtl*16 + quad*4;
      #pragma unroll
      for (int ct=0;ct<2;++ct)
        #pragma unroll
        for (int r=0;r<4;++r)
          appS[ar0 + r][ct*16 + mrow] = f2u(fmaxf(acc[rtl][ct][r], 0.f));
    }
  }
  __syncthreads();   // the only barrier

  // issue mask-frag loads early; they hide under softmax (independent of LDS)
  const unsigned short* bmp = bmF + pb*1024 + l*8;
  bf16x8 bm0 = *(const bf16x8*)bmp;
  bf16x8 bm1;
  if (w >= 4) bm1 = *(const bf16x8*)(bmp + 512);

  // ---- softmax: thread = (px = t>>4, tq = t&15 -> 4 clusters). All reads contiguous. ----
  {
    int px = t>>4, tq = t&15;
    u16x4 s4  = *(const u16x4*)&ldsP[px][tq*4];
    u16x8 shA = *(const u16x8*)&ldsP[px][64 + tq*16];
    u16x8 shB = *(const u16x8*)&ldsP[px][64 + tq*16 + 8];
    unsigned short shv[16];
    *(u16x8*)&shv[0] = shA;
    *(u16x8*)&shv[8] = shB;
    float ez[4];
    float loc = 0.f;
    #pragma unroll
    for (int j=0;j<4;++j){ ez[j] = __expf(u2f((unsigned short)s4[j])); loc += ez[j]; }
    loc += __shfl_xor(loc, 1);
    loc += __shfl_xor(loc, 2);
    loc += __shfl_xor(loc, 4);
    loc += __shfl_xor(loc, 8);       // loc = Z for this px (sum over all 64 k)
    unsigned short av[4];
    #pragma unroll
    for (int j=0;j<4;++j){
      float e0 = ez[j];
      float den = e0 + __expf(u2f(shv[j*4+0])) + __expf(u2f(shv[j*4+1]))
                     + __expf(u2f(shv[j*4+2])) + __expf(u2f(shv[j*4+3]));
      av[j] = f2u(__fdividef(e0*e0, loc*den));
    }
    int abase = (n*NB_ + pb)*2048 + px*64 + tq*4;
    *(u16x4*)(a + abase) = *(const u16x4*)av;    // one dwordx2, 128B/16-lane group
  }

  // ---- region sums via MFMA: salPart[tile][k][r] = sum_p app[k][p] * M[r][p] ----
  float* sp = salPart + (n*NB_ + pb)*(K_*R_);
  if (w < 4){
    #pragma unroll
    for (int i=0;i<2;++i){
      int rt = w*2 + i;
      bf16x8 af = *(const bf16x8*)&appS[rt*16 + mrow][quad*8];
      f32x4 r0 = (f32x4){0,0,0,0};
      r0 = __builtin_amdgcn_mfma_f32_16x16x32_bf16(af, bm0, r0, 0,0,0);
      int kb = rt*16 + quad*4;
      if (rt < 4){                       // level0: region col 0 only
        if (mrow == 0){
          #pragma unroll
          for (int r=0;r<4;++r) sp[(kb+r)*R_] = r0[r];
        }
      } else {                           // level1: cols 1..4
        if (mrow >= 1 && mrow <= 4){
          #pragma unroll
          for (int r=0;r<4;++r) sp[(kb+r-64)*R_ + mrow] = r0[r];
        }
      }
    }
  } else {
    int rt = 8 + (w-4);                  // level2: cols 5..20
    bf16x8 af = *(const bf16x8*)&appS[rt*16 + mrow][quad*8];
    f32x4 r0 = (f32x4){0,0,0,0}, r1 = (f32x4){0,0,0,0};
    r0 = __builtin_amdgcn_mfma_f32_16x16x32_bf16(af, bm0, r0, 0,0,0);
    r1 = __builtin_amdgcn_mfma_f32_16x16x32_bf16(af, bm1, r1, 0,0,0);
    int kb = rt*16 + quad*4;
    if (mrow >= 5){
      #pragma unroll
      for (int r=0;r<4;++r) sp[(kb+r-128)*R_ + mrow] = r0[r];
    } else {
      #pragma unroll
      for (int r=0;r<4;++r) sp[(kb+r-128)*R_ + 16 + mrow] = r1[r];
    }
  }
}

// ---------- K3: reduce 72 tile partials -> sal[n][k][21] ----------
__global__ __launch_bounds__(256) void k_salred(const float* __restrict__ salPart,
                                                float* __restrict__ sal){
  int tid = blockIdx.x*256 + threadIdx.x;
  if (tid >= N_*K_*R_) return;
  int n = tid / (K_*R_), i = tid - n*(K_*R_);
  const float* sp = salPart + (size_t)n*NB_*(K_*R_) + i;
  float s = 0.f;
  #pragma unroll 8
  for (int b=0;b<NB_;++b) s += sp[(size_t)b*(K_*R_)];
  sal[tid] = s;
}

// ---------- K4: vlad partials via MFMA. Block = (128-px chunk, n), 512 thr / 8 waves. ----------
__global__ __launch_bounds__(512) void k_vlad(const bf16* __restrict__ xnG,
                                              const unsigned short* __restrict__ a,
                                              const float* __restrict__ sal,
                                              float* __restrict__ vladPart,
                                              float* __restrict__ sumawPart){
  __shared__ float s_sal[K_][R_];                          // 5376 B
  __shared__ __align__(16) unsigned short awL[4][K_][40];  // 20480 B
  __shared__ float s_part[4][K_];                          // 1024 B
  int c2 = blockIdx.x, n = blockIdx.y, t = threadIdx.x;
  int p0 = c2*128;
  for (int i=t;i<K_*R_;i+=512) ((float*)s_sal)[i] = sal[(size_t)n*K_*R_ + i];
  __syncthreads();

  // ---- aw = a * (M^T sal) for this chunk: thread = (pixel pxl, 16-k group kq) ----
  {
    int pxl = t & 127, kq = t>>7;
    int pbl = pxl>>5, px = pxl&31;
    int p = p0 + pxl;
    int h = p/48, wc = p - h*48;
    bool h1[2], w1[2], h2[4], w2[4];
    #pragma unroll
    for (int i=0;i<2;++i){ h1[i] = (h>=16*i)&&(h<16*i+32); w1[i] = (wc>=16*i)&&(wc<16*i+32); }
    #pragma unroll
    for (int i=0;i<4;++i){ h2[i] = (h>=10*i-1)&&(h<10*i+19); w2[i] = (wc>=10*i-1)&&(wc<10*i+19); }
    const unsigned short* at = a + ((size_t)((n*NB_ + c2*4 + pbl)*32 + px))*K_ + kq*16;
    u16x8 av[2];
    av[0] = *(const u16x8*)at;
    av[1] = *(const u16x8*)(at + 8);
    #pragma unroll
    for (int kk=0;kk<16;++kk){
      int k = kq*16 + kk;
      float w = s_sal[k][0];
      #pragma unroll
      for (int i=0;i<2;++i) if (h1[i])
        #pragma unroll
        for (int j=0;j<2;++j) if (w1[j]) w += s_sal[k][1+2*i+j];
      #pragma unroll
      for (int i=0;i<4;++i) if (h2[i])
        #pragma unroll
        for (int j=0;j<4;++j) if (w2[j]) w += s_sal[k][5+4*i+j];
      awL[pbl][k][px] = f2u(u2f(av[kk>>3][kk&7]) * w);
    }
  }
  __syncthreads();
  // ---- row sums for sum_p(aw) ----
  if (t < 256){
    int k = t&63, qr = t>>6;
    float s = 0.f;
    #pragma unroll 8
    for (int j=0;j<32;++j) s += u2f(awL[qr][k][j]);
    s_part[qr][k] = s;
  }
  __syncthreads();

  // ---- MFMA: wave = (c-quadrant wvc, k-half mh). 16 MFMA/wave. ----
  int wave = t>>6, l = t&63, mrow = l&15, quad = l>>4;
  int wvc = wave&3, mh = wave>>2;
  f32x4 acc[2][2];
  #pragma unroll
  for (int mtl=0;mtl<2;++mtl){ acc[mtl][0] = (f32x4){0,0,0,0}; acc[mtl][1] = (f32x4){0,0,0,0}; }
  const bf16* Gf = xnG + (size_t)(n*CH_ + (c2>>1))*32768 + l*8;  // + ((ks*4+wvc)*2+half)*512
  int ksbase = (c2&1)*4;
  #pragma unroll
  for (int ksl=0;ksl<4;++ksl){
    int ks = ksbase + ksl;
    bf16x8 b0 = *(const bf16x8*)(Gf + ((ks*4+wvc)*2+0)*512);
    bf16x8 b1 = *(const bf16x8*)(Gf + ((ks*4+wvc)*2+1)*512);
    #pragma unroll
    for (int mtl=0;mtl<2;++mtl){
      bf16x8 af = *(const bf16x8*)((const bf16*)&awL[ksl][(mh*2+mtl)*16 + mrow][quad*8]);
      acc[mtl][0] = __builtin_amdgcn_mfma_f32_16x16x32_bf16(af, b0, acc[mtl][0], 0,0,0);
      acc[mtl][1] = __builtin_amdgcn_mfma_f32_16x16x32_bf16(af, b1, acc[mtl][1], 0,0,0);
    }
  }
  float* vp = vladPart + ((size_t)(n*CHV_ + c2))*(K_*C_);
  #pragma unroll
  for (int mtl=0;mtl<2;++mtl){
    #pragma unroll
    for (int ct=0;ct<2;++ct){
      int c = wvc*32 + ct*16 + mrow;
      #pragma unroll
      for (int r=0;r<4;++r){
        int k = (mh*2+mtl)*16 + quad*4 + r;
        vp[k*C_ + c] = acc[mtl][ct][r];
      }
    }
  }
  if (t < K_){
    float s = s_part[0][t] + s_part[1][t] + s_part[2][t] + s_part[3][t];
    sumawPart[((size_t)n*CHV_ + c2)*K_ + t] = s;
  }
}

// ---------- K5: fused chunk-reduce + centroid term + intra/global norms + output ----------
// One block per image, 1024 threads. No intermediate vlad buffer.
__global__ __launch_bounds__(1024) void k_vfinal(const float* __restrict__ vladPart,
                                                 const float* __restrict__ sumawPart,
                                                 const void* __restrict__ cen,
                                                 const void* __restrict__ clw,
                                                 const void* __restrict__ x,
                                                 void* __restrict__ out){
  __shared__ float s_v[K_*C_];          // 32768 B
  __shared__ float s_sw[K_];
  __shared__ float s_ssk[K_];
  __shared__ float s_scale[K_];
  __shared__ float s_gs;
  int n = blockIdx.x, t = threadIdx.x;
  int f32 = is_f32((const unsigned short*)x);

  if (t < K_){
    float sw = 0.f;
    #pragma unroll
    for (int ch=0;ch<CHV_;++ch) sw += sumawPart[((size_t)n*CHV_ + ch)*K_ + t];
    s_sw[t] = sw;
  }
  __syncthreads();
  {
    const float* vpn = vladPart + (size_t)n*CHV_*(K_*C_);
    for (int i=t;i<K_*C_;i+=1024){
      float s = 0.f;
      #pragma unroll
      for (int ch=0;ch<CHV_;++ch) s += vpn[(size_t)ch*(K_*C_) + i];
      float cv = f32 ? ((const float*)cen)[i] : b2f(((const bf16*)cen)[i]);
      s_v[i] = s - cv*s_sw[i>>7];
    }
  }
  __syncthreads();
  {
    int k = t>>4, q = t&15;               // 16 threads per cluster, 8 elems each
    float ss = 0.f;
    #pragma unroll
    for (int mm=0;mm<8;++mm){ float v = s_v[k*C_ + q + 16*mm]; ss += v*v; }
    ss += __shfl_down(ss, 8);
    ss += __shfl_down(ss, 4);
    ss += __shfl_down(ss, 2);
    ss += __shfl_down(ss, 1);
    if (q == 0) s_ssk[k] = ss;
  }
  __syncthreads();
  if (t < K_){
    float cw = f32 ? ((const float*)clw)[t] : b2f(((const bf16*)clw)[t]);
    s_scale[t] = cw / fmaxf(sqrtf(s_ssk[t]), 1e-12f);
  }
  __syncthreads();
  if (t == 0){
    float gss = 0.f;
    for (int kk=0;kk<K_;++kk) gss += s_ssk[kk]*s_scale[kk]*s_scale[kk];
    s_gs = 1.f / fmaxf(sqrtf(gss), 1e-12f);
  }
  __syncthreads();
  float gsc = s_gs;
  if (f32){
    float* op = (float*)out + (size_t)n*K_*C_;
    for (int i=t;i<K_*C_;i+=1024) op[i] = s_v[i]*s_scale[i>>7]*gsc;
  } else {
    bf16* op = (bf16*)out + (size_t)n*K_*C_;
    for (int i=t;i<K_*C_;i+=1024) op[i] = __float2bfloat16(s_v[i]*s_scale[i>>7]*gsc);
  }
}

extern "C" void kernel_launch(void* const* d_in, const int* in_sizes, int n_in,
                              void* d_out, int out_size, void* d_ws, size_t ws_size,
                              hipStream_t stream){
  const void* x   = d_in[0];
  const void* cen = d_in[1];
  const void* cvw = d_in[2];
  const void* csw = d_in[3];
  const void* caw = d_in[4];
  const void* clw = d_in[5];

  char* ws = (char*)d_ws;
  bf16* WallF = (bf16*)ws;             ws += (size_t)M_*C_*2;        // 128 KB
  bf16* xnF   = (bf16*)ws;             ws += (size_t)N_*P_*C_*2;     // 18.87 MB
  bf16* xnG   = (bf16*)ws;             ws += (size_t)N_*C_*P_*2;     // 18.87 MB
  unsigned short* a = (unsigned short*)ws;  ws += (size_t)N_*K_*P_*2; // 9.44 MB
  float* sal  = (float*)ws;            ws += (size_t)N_*K_*R_*4;     // 0.17 MB
  char* un = ws;
  float* salPart   = (float*)un;               // dead after k_salred
  float* sumawPart = (float*)un;               // overlay: written by k_vlad (147 KB)
  ws += (size_t)N_*NB_*K_*R_*4;                                      // 12.39 MB
  unsigned short* bmF = (unsigned short*)ws; ws += (size_t)NB_*2*512*2; // 147 KB
  // vladPart overlays xnF (dead after k_gemm); N_*CHV_*K_*C_*4 == N_*P_*C_*2 exactly.
  float* vladPart = (float*)xnF;

  k_prep  <<<dim3(WBLK_ + M_*C_/256 + MBLK_), 256, 0, stream>>>(cvw, csw, caw, x,
                                                                WallF, xnF, xnG, bmF);
  k_gemm  <<<dim3(NB_, N_),           512, 0, stream>>>(WallF, xnF, bmF, a, salPart);
  k_salred<<<dim3((N_*K_*R_+255)/256), 256, 0, stream>>>(salPart, sal);
  k_vlad  <<<dim3(CHV_, N_),          512, 0, stream>>>(xnG, a, sal, vladPart, sumawPart);
  k_vfinal<<<dim3(N_),               1024, 0, stream>>>(vladPart, sumawPart, cen, clw, x, d_out);
}